// Round 15
// baseline (588.263 us; speedup 1.0000x reference)
//
#include <hip/hip_runtime.h>
#include <hip/hip_bf16.h>
#include <math.h>

typedef __attribute__((ext_vector_type(8))) short bf16x8;
typedef __attribute__((ext_vector_type(4))) float f32x4;

#define GLB_CAST(p) ((const __attribute__((address_space(1))) void*)(p))
#define LDS_CAST(p) ((__attribute__((address_space(3))) void*)(p))

static __device__ __forceinline__ unsigned short bf16_bits(float x) {
    __hip_bfloat16 h = __float2bfloat16(x);
    return *(unsigned short*)&h;
}

// Q pre-scale: (1/sqrt(128)) * log2(e) -> flash softmax runs in log2 domain
#define QSC 0.127517455f
#define THR_LOG2 11.5415605f   // 8 * log2(e)

// ---------------- fp32 -> bf16 convert, all 5 inputs in one dispatch ----------------
__global__ void cvt_all(const float* __restrict__ x,  const float* __restrict__ wq,
                        const float* __restrict__ wk, const float* __restrict__ wv,
                        const float* __restrict__ wo,
                        __hip_bfloat16* __restrict__ xb,  __hip_bfloat16* __restrict__ wqb,
                        __hip_bfloat16* __restrict__ wkb, __hip_bfloat16* __restrict__ wvb,
                        __hip_bfloat16* __restrict__ wob)
{
    const size_t NX = 8388608, NW = 4194304;
    size_t i = ((size_t)blockIdx.x * 256 + threadIdx.x) * 8;
    const float* s; __hip_bfloat16* d; size_t off;
    if (i < NX) { s = x; d = xb; off = i; }
    else {
        size_t k = i - NX;
        const int seg = (int)(k >> 22);
        off = k & (NW - 1);
        s = seg == 0 ? wq : seg == 1 ? wk : seg == 2 ? wv : wo;
        d = seg == 0 ? wqb : seg == 1 ? wkb : seg == 2 ? wvb : wob;
    }
    float4 a = *(const float4*)(s + off);
    float4 b = *(const float4*)(s + off + 4);
    float t[8] = {a.x, a.y, a.z, a.w, b.x, b.y, b.z, b.w};
    union { unsigned short u[8]; uint4 v; } o;
#pragma unroll
    for (int j = 0; j < 8; ++j) o.u[j] = bf16_bits(t[j]);
    *(uint4*)(d + off) = o.v;
}

// ---------------- fused QKV GEMM + RoPE epilogue (round-11 proven form) ----------------
__global__ __launch_bounds__(256, 2)
void gemm_qkv(const __hip_bfloat16* __restrict__ A,
              const __hip_bfloat16* __restrict__ Wq,
              const __hip_bfloat16* __restrict__ Wk,
              const __hip_bfloat16* __restrict__ Wv,
              __hip_bfloat16* __restrict__ Qo,
              __hip_bfloat16* __restrict__ Ko,
              __hip_bfloat16* __restrict__ Vto)
{
    const int K = 2048;
    __shared__ __hip_bfloat16 As[128 * 32];
    __shared__ __hip_bfloat16 Bs[128 * 32];
    __shared__ __hip_bfloat16 Ct[128 * 128];   // rope exchange tile (dead during K-loop)
    const int tid = threadIdx.x;
    const int w = tid >> 6, l = tid & 63;
    const int sel = blockIdx.y >> 4;
    const __hip_bfloat16* Bt = sel == 0 ? Wq : (sel == 1 ? Wk : Wv);
    const int m0 = blockIdx.x * 128, n0 = (blockIdx.y & 15) * 128;
    const int wr = w >> 1, wc = w & 1;
    const int lr = l & 15, kh = l >> 4;

    f32x4 acc[4][4] = {};

    for (int kt = 0; kt < 64; ++kt) {
        const int kb = kt * 32;
#pragma unroll
        for (int i = 0; i < 2; ++i) {
            const int s = i * 256 + tid;
            const int r = s >> 2, ks = (s & 3) * 8;
            __builtin_amdgcn_global_load_lds(GLB_CAST(A + (size_t)(m0 + r) * K + kb + ks),
                                             LDS_CAST(As + (size_t)(i * 256 + w * 64) * 8),
                                             16, 0, 0);
            __builtin_amdgcn_global_load_lds(GLB_CAST(Bt + (size_t)(n0 + r) * K + kb + ks),
                                             LDS_CAST(Bs + (size_t)(i * 256 + w * 64) * 8),
                                             16, 0, 0);
        }
        __syncthreads();
        bf16x8 af[4], bfr[4];
#pragma unroll
        for (int m = 0; m < 4; ++m)
            af[m] = *(const bf16x8*)(As + (wr * 64 + m * 16 + lr) * 32 + kh * 8);
#pragma unroll
        for (int n = 0; n < 4; ++n)
            bfr[n] = *(const bf16x8*)(Bs + (wc * 64 + n * 16 + lr) * 32 + kh * 8);
#pragma unroll
        for (int m = 0; m < 4; ++m)
#pragma unroll
            for (int n = 0; n < 4; ++n)
                acc[m][n] = __builtin_amdgcn_mfma_f32_16x16x32_bf16(af[m], bfr[n], acc[m][n], 0, 0, 0);
        __syncthreads();
    }

    const int h = n0 >> 7;  // head index
    if (sel < 2) {
        __hip_bfloat16* Cout = sel == 0 ? Qo : Ko;
        const float osc = (sel == 0) ? QSC : 1.0f;
#pragma unroll
        for (int m = 0; m < 4; ++m)
#pragma unroll
            for (int n = 0; n < 4; ++n)
#pragma unroll
                for (int j = 0; j < 4; ++j)
                    Ct[(wr * 64 + m * 16 + kh * 4 + j) * 128 + wc * 64 + n * 16 + lr] =
                        __float2bfloat16(acc[m][n][j]);
        __syncthreads();
        float inv_n[4];
#pragma unroll
        for (int n = 0; n < 4; ++n) {
            const int c = wc * 64 + n * 16 + lr;
            inv_n[n] = __expf((float)(c & 63) * (-0.14391156831212787f)); // -ln(10000)/64
        }
#pragma unroll
        for (int m = 0; m < 4; ++m) {
#pragma unroll
            for (int j = 0; j < 4; ++j) {
                const int rl = wr * 64 + m * 16 + kh * 4 + j;
                const int r = m0 + rl;
                const int b = r >> 11, sy = r & 2047;
                const float fs = (float)sy;
#pragma unroll
                for (int n = 0; n < 4; ++n) {
                    const int c = wc * 64 + n * 16 + lr;
                    float sn, cs;
                    __sincosf(fs * inv_n[n], &sn, &cs);
                    const float own = acc[m][n][j];
                    const float partner = __bfloat162float(Ct[rl * 128 + (c ^ 64)]);
                    const float outv = (c < 64) ? own * cs - partner * sn
                                                : own * cs + partner * sn;
                    Cout[((size_t)(b * 16 + h) * 2048 + sy) * 128 + c] =
                        __float2bfloat16(outv * osc);
                }
            }
        }
    } else {
#pragma unroll
        for (int m = 0; m < 4; ++m) {
            const int r0 = m0 + wr * 64 + m * 16 + kh * 4;
#pragma unroll
            for (int n = 0; n < 4; ++n) {
                const int c = wc * 64 + n * 16 + lr;
#pragma unroll
                for (int j = 0; j < 4; ++j) {
                    const int r = r0 + j;
                    const int b = r >> 11, sy = r & 2047;
                    Vto[((size_t)(b * 16 + h) * 128 + c) * 2048 + sy] =
                        __float2bfloat16(acc[m][n][j]);
                }
            }
        }
    }
}

// ---------------- O-projection GEMM: fp32 out [4096][2048] (m97 structure) ----------------
__global__ __launch_bounds__(256, 2)
void gemm_o(const __hip_bfloat16* __restrict__ A,
            const __hip_bfloat16* __restrict__ Bt,
            float* __restrict__ Cout)
{
    const int K = 2048;
    __shared__ __hip_bfloat16 As[128 * 32];
    __shared__ __hip_bfloat16 Bs[128 * 32];
    const int tid = threadIdx.x;
    const int w = tid >> 6, l = tid & 63;
    const int m0 = blockIdx.x * 128, n0 = blockIdx.y * 128;
    const int wr = w >> 1, wc = w & 1;
    const int lr = l & 15, kh = l >> 4;

    f32x4 acc[4][4] = {};

    for (int kt = 0; kt < 64; ++kt) {
        const int kb = kt * 32;
#pragma unroll
        for (int i = 0; i < 2; ++i) {
            const int s = i * 256 + tid;
            const int r = s >> 2, ks = (s & 3) * 8;
            __builtin_amdgcn_global_load_lds(GLB_CAST(A + (size_t)(m0 + r) * K + kb + ks),
                                             LDS_CAST(As + (size_t)(i * 256 + w * 64) * 8),
                                             16, 0, 0);
            __builtin_amdgcn_global_load_lds(GLB_CAST(Bt + (size_t)(n0 + r) * K + kb + ks),
                                             LDS_CAST(Bs + (size_t)(i * 256 + w * 64) * 8),
                                             16, 0, 0);
        }
        __syncthreads();
        bf16x8 af[4], bfr[4];
#pragma unroll
        for (int m = 0; m < 4; ++m)
            af[m] = *(const bf16x8*)(As + (wr * 64 + m * 16 + lr) * 32 + kh * 8);
#pragma unroll
        for (int n = 0; n < 4; ++n)
            bfr[n] = *(const bf16x8*)(Bs + (wc * 64 + n * 16 + lr) * 32 + kh * 8);
#pragma unroll
        for (int m = 0; m < 4; ++m)
#pragma unroll
            for (int n = 0; n < 4; ++n)
                acc[m][n] = __builtin_amdgcn_mfma_f32_16x16x32_bf16(af[m], bfr[n], acc[m][n], 0, 0, 0);
        __syncthreads();
    }

#pragma unroll
    for (int m = 0; m < 4; ++m) {
        const int r0 = m0 + wr * 64 + m * 16 + kh * 4;
#pragma unroll
        for (int n = 0; n < 4; ++n) {
            const int c = n0 + wc * 64 + n * 16 + lr;
#pragma unroll
            for (int j = 0; j < 4; ++j)
                Cout[(size_t)(r0 + j) * 2048 + c] = acc[m][n][j];
        }
    }
}

// ---------------- causal flash attention: 4 waves x 32 q-rows, KVBLK=32, 5 blocks/CU ----------------
// 32KB LDS/block -> 5 blocks/CU resident (20 waves/CU, 5 waves/SIMD) for chain hiding.
// Deferred lrow (lane-partial, epilogue reduce) + lazy pmax (reduce only when threshold busts).
__global__ __launch_bounds__(256, 5)
void flash_part(const __hip_bfloat16* __restrict__ Q,
                const __hip_bfloat16* __restrict__ K,
                const __hip_bfloat16* __restrict__ Vt,
                __hip_bfloat16* __restrict__ AO,
                __hip_bfloat16* __restrict__ OP,
                float* __restrict__ ML)
{
    const int bh = blockIdx.x;
    const int u  = blockIdx.y;
    const int tid = threadIdx.x, w = tid >> 6, l = tid & 63;
    const int lr = l & 15, hi = l >> 4;

    int G, part, P;
    if (u < 16)      { G = 12 + (u >> 2);            part = u & 3;   P = 4; }
    else if (u < 28) { int v = u - 16; G = 8 + v / 3; part = v % 3;  P = 3; }
    else if (u < 36) { int v = u - 28; G = 4 + (v >> 1); part = v & 1; P = 2; }
    else             { G = u - 36;                   part = 0;       P = 1; }
    const int nt = 4 * G + 4;                        // tiles of 32 kv
    const int t0 = (part * nt) / P, t1 = ((part + 1) * nt) / P;
    const bool split = (P > 1);
    const int qb = G * 128 + w * 32;
    const int q0 = qb + lr, q1 = qb + 16 + lr;

    const __hip_bfloat16* Qb = Q  + (size_t)bh * 2048 * 128;
    const __hip_bfloat16* Kb = K  + (size_t)bh * 2048 * 128;
    const __hip_bfloat16* Vb = Vt + (size_t)bh * 128 * 2048;

    __shared__ __align__(16) __hip_bfloat16 Ks[2][32 * 128];
    __shared__ __align__(16) __hip_bfloat16 Vs[2][128 * 32];

    bf16x8 qf[2][4];
#pragma unroll
    for (int g = 0; g < 2; ++g)
#pragma unroll
        for (int kk = 0; kk < 4; ++kk)
            qf[g][kk] = *(const bf16x8*)(Qb + (size_t)(qb + g * 16 + lr) * 128 + kk * 32 + hi * 8);

    int rK[2], cK[2], rV[2], cV[2];
#pragma unroll
    for (int i = 0; i < 2; ++i) {
        const int ci = i * 4 + w;
        rK[i] = ci * 4 + (l >> 4);
        cK[i] = ((l & 15) ^ (rK[i] & 7)) * 8;
        rV[i] = ci * 16 + (l >> 2);
        cV[i] = ((l & 3) ^ (rV[i] & 3)) * 8;
    }
    const int rsw7 = lr & 7, vsw3 = lr & 3;
    const int sA = lr + ((hi & 1) << 5);
    const int sB = sA + 16;
    const bool plo = (hi < 2);

#define STAGE(buf, t)                                                                        \
    {                                                                                        \
        const int kv0_ = (t) * 32;                                                           \
        _Pragma("unroll")                                                                    \
        for (int i = 0; i < 2; ++i) {                                                        \
            __builtin_amdgcn_global_load_lds(                                                \
                GLB_CAST(Kb + (size_t)(kv0_ + rK[i]) * 128 + cK[i]),                         \
                LDS_CAST(&Ks[buf][(i * 4 + w) * 512]), 16, 0, 0);                            \
            __builtin_amdgcn_global_load_lds(                                                \
                GLB_CAST(Vb + (size_t)rV[i] * 2048 + kv0_ + cV[i]),                          \
                LDS_CAST(&Vs[buf][(i * 4 + w) * 512]), 16, 0, 0);                            \
        }                                                                                    \
    }

    f32x4 o[2][8] = {};
    float mrow[2] = {-1e30f, -1e30f};
    float lrow[2] = {0.f, 0.f};   // lane-partial sums (deferred reduction)

    int cur = 0;
    STAGE(0, t0);
    __syncthreads();

    for (int t = t0; t < t1; ++t) {
        if (t + 1 < t1) STAGE(cur ^ 1, t + 1);
        const __hip_bfloat16* Kc = &Ks[cur][0];
        const __hip_bfloat16* Vc = &Vs[cur][0];
        const int kv0 = t * 32;

        f32x4 sT[2][2] = {};
        __builtin_amdgcn_s_setprio(1);
#pragma unroll
        for (int f = 0; f < 2; ++f)
#pragma unroll
            for (int kk = 0; kk < 4; ++kk) {
                const bf16x8 kf = *(const bf16x8*)(Kc + (f * 16 + lr) * 128 +
                                                   ((kk * 4 + hi) ^ rsw7) * 8);
                sT[0][f] = __builtin_amdgcn_mfma_f32_16x16x32_bf16(kf, qf[0][kk], sT[0][f], 0, 0, 0);
                sT[1][f] = __builtin_amdgcn_mfma_f32_16x16x32_bf16(kf, qf[1][kk], sT[1][f], 0, 0, 0);
            }
        __builtin_amdgcn_s_setprio(0);

        // causal mask only on diagonal tiles (wave-uniform branch)
        if (kv0 + 31 > qb) {
#pragma unroll
            for (int g = 0; g < 2; ++g) {
                const int qown = g ? q1 : q0;
#pragma unroll
                for (int f = 0; f < 2; ++f)
#pragma unroll
                    for (int j = 0; j < 4; ++j) {
                        const int kv = kv0 + f * 16 + hi * 4 + j;
                        if (kv > qown) sT[g][f][j] = -1e30f;
                    }
            }
        }

        // lane-local max (lazy: no cross-lane reduce unless threshold busts)
        float lmax[2];
#pragma unroll
        for (int g = 0; g < 2; ++g) {
            float mx = sT[g][0][0];
#pragma unroll
            for (int f = 0; f < 2; ++f)
#pragma unroll
                for (int j = 0; j < 4; ++j) mx = fmaxf(mx, sT[g][f][j]);
            lmax[g] = mx;
        }

        if (!__all(lmax[0] <= mrow[0] + THR_LOG2 && lmax[1] <= mrow[1] + THR_LOG2)) {
#pragma unroll
            for (int g = 0; g < 2; ++g) {
                float pm = lmax[g];
                pm = fmaxf(pm, __shfl_xor(pm, 16));
                pm = fmaxf(pm, __shfl_xor(pm, 32));
                const float mnew = fmaxf(mrow[g], pm);
                const float alpha = exp2f(mrow[g] - mnew);
                mrow[g] = mnew;
                lrow[g] *= alpha;    // partial sums scale by the same row-uniform alpha
                float aj[4];
#pragma unroll
                for (int j = 0; j < 4; ++j)
                    aj[j] = __shfl(alpha, (l & 48) | (hi * 4 + j), 64);
#pragma unroll
                for (int dn = 0; dn < 8; ++dn)
#pragma unroll
                    for (int j = 0; j < 4; ++j) o[g][dn][j] *= aj[j];
            }
        }

        // P = exp2(S - m); accumulate lane-partial row sums (no per-tile reduce)
#pragma unroll
        for (int g = 0; g < 2; ++g) {
            float rs = 0.f;
#pragma unroll
            for (int f = 0; f < 2; ++f)
#pragma unroll
                for (int j = 0; j < 4; ++j) {
                    const float pv = exp2f(sT[g][f][j] - mrow[g]);
                    sT[g][f][j] = pv;
                    rs += pv;
                }
            lrow[g] += rs;
        }

        union { unsigned u[4]; bf16x8 v; } pf[2];
#pragma unroll
        for (int g = 0; g < 2; ++g) {
            unsigned wds[4];
#pragma unroll
            for (int i = 0; i < 4; ++i)
                wds[i] = (unsigned)bf16_bits(sT[g][i >> 1][(i & 1) * 2]) |
                         ((unsigned)bf16_bits(sT[g][i >> 1][(i & 1) * 2 + 1]) << 16);
            const unsigned a0 = __shfl((int)wds[0], sA, 64), a1 = __shfl((int)wds[1], sA, 64);
            const unsigned a2 = __shfl((int)wds[2], sA, 64), a3 = __shfl((int)wds[3], sA, 64);
            const unsigned b0 = __shfl((int)wds[0], sB, 64), b1 = __shfl((int)wds[1], sB, 64);
            const unsigned b2 = __shfl((int)wds[2], sB, 64), b3 = __shfl((int)wds[3], sB, 64);
            pf[g].u[0] = plo ? a0 : a2;
            pf[g].u[1] = plo ? a1 : a3;
            pf[g].u[2] = plo ? b0 : b2;
            pf[g].u[3] = plo ? b1 : b3;
        }

        __builtin_amdgcn_s_setprio(1);
#pragma unroll
        for (int dn = 0; dn < 8; ++dn) {
            const bf16x8 vf = *(const bf16x8*)(Vc + (dn * 16 + lr) * 32 + (hi ^ vsw3) * 8);
            o[0][dn] = __builtin_amdgcn_mfma_f32_16x16x32_bf16(pf[0].v, vf, o[0][dn], 0, 0, 0);
            o[1][dn] = __builtin_amdgcn_mfma_f32_16x16x32_bf16(pf[1].v, vf, o[1][dn], 0, 0, 0);
        }
        __builtin_amdgcn_s_setprio(0);

        __syncthreads();
        cur ^= 1;
    }
#undef STAGE

    // finalize lane-partial row sums -> row totals (uniform across the row's 4 lanes)
#pragma unroll
    for (int g = 0; g < 2; ++g) {
        lrow[g] += __shfl_xor(lrow[g], 16);
        lrow[g] += __shfl_xor(lrow[g], 32);
    }

    if (!split) {
#pragma unroll
        for (int g = 0; g < 2; ++g) {
            float linv[4];
#pragma unroll
            for (int j = 0; j < 4; ++j)
                linv[j] = 1.0f / __shfl(lrow[g], (l & 48) | (hi * 4 + j), 64);
#pragma unroll
            for (int j = 0; j < 4; ++j) {
                const int q = qb + g * 16 + hi * 4 + j;
                const size_t rb = ((size_t)(bh >> 4) * 2048 + q) * 2048 + (size_t)(bh & 15) * 128;
#pragma unroll
                for (int dn = 0; dn < 8; ++dn)
                    AO[rb + dn * 16 + lr] = __float2bfloat16(o[g][dn][j] * linv[j]);
            }
        }
    } else {
        const int base = (G < 8) ? (G - 4) * 2 : ((G < 12) ? 8 + (G - 8) * 3
                                                           : 20 + (G - 12) * 4);
        const int pidx = bh * 36 + base + part;
#pragma unroll
        for (int g = 0; g < 2; ++g) {
#pragma unroll
            for (int j = 0; j < 4; ++j) {
                const int row = w * 32 + g * 16 + hi * 4 + j;
#pragma unroll
                for (int dn = 0; dn < 8; ++dn)
                    OP[((size_t)pidx * 128 + row) * 128 + dn * 16 + lr] =
                        __float2bfloat16(o[g][dn][j]);
            }
            if (l < 16) {
                const int row = w * 32 + g * 16 + l;
                ML[((size_t)pidx * 128 + row) * 2]     = mrow[g];   // log2-domain m
                ML[((size_t)pidx * 128 + row) * 2 + 1] = lrow[g];   // row total
            }
        }
    }
}

// ---------------- merge P in {2,3,4} partials per split group (G=4..15) ----------------
__global__ void flash_merge(const __hip_bfloat16* __restrict__ OP,
                            const float* __restrict__ ML,
                            __hip_bfloat16* __restrict__ AO)
{
    const int gi = blockIdx.x % 12, bh = blockIdx.x / 12;
    const int G = 4 + gi;
    const int P = (G < 8) ? 2 : ((G < 12) ? 3 : 4);
    const int base = (G < 8) ? (G - 4) * 2 : ((G < 12) ? 8 + (G - 8) * 3
                                                       : 20 + (G - 12) * 4);
    const int pidx0 = bh * 36 + base;
    const int t = threadIdx.x, r = t >> 1, c0 = (t & 1) * 64;

    float m[4], lv[4];
    float M = -1e30f;
#pragma unroll
    for (int p = 0; p < 4; ++p) if (p < P) {
        m[p]  = ML[((size_t)(pidx0 + p) * 128 + r) * 2];
        lv[p] = ML[((size_t)(pidx0 + p) * 128 + r) * 2 + 1];
        M = fmaxf(M, m[p]);
    }
    float wgt[4];
    float den = 0.f;
#pragma unroll
    for (int p = 0; p < 4; ++p) if (p < P) {
        wgt[p] = exp2f(m[p] - M);   // log2-domain merge
        den += lv[p] * wgt[p];
    }
    const float inv = 1.0f / den;

    const int q = G * 128 + r;
    __hip_bfloat16* out = AO + ((size_t)(bh >> 4) * 2048 + q) * 2048 + (size_t)(bh & 15) * 128 + c0;

#pragma unroll
    for (int ch = 0; ch < 8; ++ch) {
        float acc[8] = {0.f, 0.f, 0.f, 0.f, 0.f, 0.f, 0.f, 0.f};
#pragma unroll
        for (int p = 0; p < 4; ++p) if (p < P) {
            const bf16x8 v = *(const bf16x8*)(OP + ((size_t)(pidx0 + p) * 128 + r) * 128 + c0 + ch * 8);
#pragma unroll
            for (int i = 0; i < 8; ++i) {
                __hip_bfloat16 hv;
                *(short*)&hv = v[i];
                acc[i] += __bfloat162float(hv) * wgt[p];
            }
        }
        union { unsigned short us[8]; bf16x8 v; } rr;
#pragma unroll
        for (int i = 0; i < 8; ++i) rr.us[i] = bf16_bits(acc[i] * inv);
        *(bf16x8*)(out + ch * 8) = rr.v;
    }
}

extern "C" void kernel_launch(void* const* d_in, const int* in_sizes, int n_in,
                              void* d_out, int out_size, void* d_ws, size_t ws_size,
                              hipStream_t stream) {
    (void)in_sizes; (void)n_in; (void)out_size; (void)ws_size;
    const float* x  = (const float*)d_in[0];
    const float* Wq = (const float*)d_in[1];
    const float* Wk = (const float*)d_in[2];
    const float* Wv = (const float*)d_in[3];
    const float* Wo = (const float*)d_in[4];

    char* p = (char*)d_ws;
    auto carve = [&](size_t bytes) -> char* {
        char* r = p;
        p += (bytes + 255) & ~(size_t)255;
        return r;
    };
    __hip_bfloat16* xb  = (__hip_bfloat16*)carve(4096ull * 2048 * 2);  // reused as AO
    __hip_bfloat16* Wqb = (__hip_bfloat16*)carve(2048ull * 2048 * 2);
    __hip_bfloat16* Wkb = (__hip_bfloat16*)carve(2048ull * 2048 * 2);
    __hip_bfloat16* Wvb = (__hip_bfloat16*)carve(2048ull * 2048 * 2);
    __hip_bfloat16* Wob = (__hip_bfloat16*)carve(2048ull * 2048 * 2);
    __hip_bfloat16* Qb  = (__hip_bfloat16*)carve(32ull * 2048 * 128 * 2);
    __hip_bfloat16* Kb  = (__hip_bfloat16*)carve(32ull * 2048 * 128 * 2);
    __hip_bfloat16* Vtb = (__hip_bfloat16*)carve(32ull * 128 * 2048 * 2);
    __hip_bfloat16* OPb = (__hip_bfloat16*)carve(32ull * 36 * 128 * 128 * 2);  // partial O
    float*          MLb = (float*)carve(32ull * 36 * 128 * 2 * 4);             // partial m,l

    cvt_all<<<12288, 256, 0, stream>>>(x, Wq, Wk, Wv, Wo, xb, Wqb, Wkb, Wvb, Wob);

    gemm_qkv<<<dim3(32, 48), 256, 0, stream>>>(xb, Wqb, Wkb, Wvb, Qb, Kb, Vtb);

    flash_part<<<dim3(32, 40), 256, 0, stream>>>(Qb, Kb, Vtb, xb /* AO */, OPb, MLb);
    flash_merge<<<384, 256, 0, stream>>>(OPb, MLb, xb /* AO */);

    gemm_o<<<dim3(32, 16), 256, 0, stream>>>(xb, Wob, (float*)d_out);
}

// Round 16
// 286.645 us; speedup vs baseline: 2.0522x; 2.0522x over previous
//
#include <hip/hip_runtime.h>
#include <hip/hip_bf16.h>
#include <math.h>

typedef __attribute__((ext_vector_type(8))) short bf16x8;
typedef __attribute__((ext_vector_type(4))) float f32x4;

#define GLB_CAST(p) ((const __attribute__((address_space(1))) void*)(p))
#define LDS_CAST(p) ((__attribute__((address_space(3))) void*)(p))

static __device__ __forceinline__ unsigned short bf16_bits(float x) {
    __hip_bfloat16 h = __float2bfloat16(x);
    return *(unsigned short*)&h;
}

// Q pre-scale: (1/sqrt(128)) * log2(e) -> flash softmax runs in log2 domain
#define QSC 0.127517455f
#define THR_LOG2 11.5415605f   // 8 * log2(e)

// ---------------- fp32 -> bf16 convert, all 5 inputs in one dispatch ----------------
__global__ void cvt_all(const float* __restrict__ x,  const float* __restrict__ wq,
                        const float* __restrict__ wk, const float* __restrict__ wv,
                        const float* __restrict__ wo,
                        __hip_bfloat16* __restrict__ xb,  __hip_bfloat16* __restrict__ wqb,
                        __hip_bfloat16* __restrict__ wkb, __hip_bfloat16* __restrict__ wvb,
                        __hip_bfloat16* __restrict__ wob)
{
    const size_t NX = 8388608, NW = 4194304;
    size_t i = ((size_t)blockIdx.x * 256 + threadIdx.x) * 8;
    const float* s; __hip_bfloat16* d; size_t off;
    if (i < NX) { s = x; d = xb; off = i; }
    else {
        size_t k = i - NX;
        const int seg = (int)(k >> 22);
        off = k & (NW - 1);
        s = seg == 0 ? wq : seg == 1 ? wk : seg == 2 ? wv : wo;
        d = seg == 0 ? wqb : seg == 1 ? wkb : seg == 2 ? wvb : wob;
    }
    float4 a = *(const float4*)(s + off);
    float4 b = *(const float4*)(s + off + 4);
    float t[8] = {a.x, a.y, a.z, a.w, b.x, b.y, b.z, b.w};
    union { unsigned short u[8]; uint4 v; } o;
#pragma unroll
    for (int j = 0; j < 8; ++j) o.u[j] = bf16_bits(t[j]);
    *(uint4*)(d + off) = o.v;
}

// ---------------- fused QKV GEMM + RoPE epilogue (round-11 proven form) ----------------
__global__ __launch_bounds__(256, 2)
void gemm_qkv(const __hip_bfloat16* __restrict__ A,
              const __hip_bfloat16* __restrict__ Wq,
              const __hip_bfloat16* __restrict__ Wk,
              const __hip_bfloat16* __restrict__ Wv,
              __hip_bfloat16* __restrict__ Qo,
              __hip_bfloat16* __restrict__ Ko,
              __hip_bfloat16* __restrict__ Vto)
{
    const int K = 2048;
    __shared__ __hip_bfloat16 As[128 * 32];
    __shared__ __hip_bfloat16 Bs[128 * 32];
    __shared__ __hip_bfloat16 Ct[128 * 128];   // rope exchange tile (dead during K-loop)
    const int tid = threadIdx.x;
    const int w = tid >> 6, l = tid & 63;
    const int sel = blockIdx.y >> 4;
    const __hip_bfloat16* Bt = sel == 0 ? Wq : (sel == 1 ? Wk : Wv);
    const int m0 = blockIdx.x * 128, n0 = (blockIdx.y & 15) * 128;
    const int wr = w >> 1, wc = w & 1;
    const int lr = l & 15, kh = l >> 4;

    f32x4 acc[4][4] = {};

    for (int kt = 0; kt < 64; ++kt) {
        const int kb = kt * 32;
#pragma unroll
        for (int i = 0; i < 2; ++i) {
            const int s = i * 256 + tid;
            const int r = s >> 2, ks = (s & 3) * 8;
            __builtin_amdgcn_global_load_lds(GLB_CAST(A + (size_t)(m0 + r) * K + kb + ks),
                                             LDS_CAST(As + (size_t)(i * 256 + w * 64) * 8),
                                             16, 0, 0);
            __builtin_amdgcn_global_load_lds(GLB_CAST(Bt + (size_t)(n0 + r) * K + kb + ks),
                                             LDS_CAST(Bs + (size_t)(i * 256 + w * 64) * 8),
                                             16, 0, 0);
        }
        __syncthreads();
        bf16x8 af[4], bfr[4];
#pragma unroll
        for (int m = 0; m < 4; ++m)
            af[m] = *(const bf16x8*)(As + (wr * 64 + m * 16 + lr) * 32 + kh * 8);
#pragma unroll
        for (int n = 0; n < 4; ++n)
            bfr[n] = *(const bf16x8*)(Bs + (wc * 64 + n * 16 + lr) * 32 + kh * 8);
#pragma unroll
        for (int m = 0; m < 4; ++m)
#pragma unroll
            for (int n = 0; n < 4; ++n)
                acc[m][n] = __builtin_amdgcn_mfma_f32_16x16x32_bf16(af[m], bfr[n], acc[m][n], 0, 0, 0);
        __syncthreads();
    }

    const int h = n0 >> 7;  // head index
    if (sel < 2) {
        __hip_bfloat16* Cout = sel == 0 ? Qo : Ko;
        const float osc = (sel == 0) ? QSC : 1.0f;
#pragma unroll
        for (int m = 0; m < 4; ++m)
#pragma unroll
            for (int n = 0; n < 4; ++n)
#pragma unroll
                for (int j = 0; j < 4; ++j)
                    Ct[(wr * 64 + m * 16 + kh * 4 + j) * 128 + wc * 64 + n * 16 + lr] =
                        __float2bfloat16(acc[m][n][j]);
        __syncthreads();
        float inv_n[4];
#pragma unroll
        for (int n = 0; n < 4; ++n) {
            const int c = wc * 64 + n * 16 + lr;
            inv_n[n] = __expf((float)(c & 63) * (-0.14391156831212787f)); // -ln(10000)/64
        }
#pragma unroll
        for (int m = 0; m < 4; ++m) {
#pragma unroll
            for (int j = 0; j < 4; ++j) {
                const int rl = wr * 64 + m * 16 + kh * 4 + j;
                const int r = m0 + rl;
                const int b = r >> 11, sy = r & 2047;
                const float fs = (float)sy;
#pragma unroll
                for (int n = 0; n < 4; ++n) {
                    const int c = wc * 64 + n * 16 + lr;
                    float sn, cs;
                    __sincosf(fs * inv_n[n], &sn, &cs);
                    const float own = acc[m][n][j];
                    const float partner = __bfloat162float(Ct[rl * 128 + (c ^ 64)]);
                    const float outv = (c < 64) ? own * cs - partner * sn
                                                : own * cs + partner * sn;
                    Cout[((size_t)(b * 16 + h) * 2048 + sy) * 128 + c] =
                        __float2bfloat16(outv * osc);
                }
            }
        }
    } else {
#pragma unroll
        for (int m = 0; m < 4; ++m) {
            const int r0 = m0 + wr * 64 + m * 16 + kh * 4;
#pragma unroll
            for (int n = 0; n < 4; ++n) {
                const int c = wc * 64 + n * 16 + lr;
#pragma unroll
                for (int j = 0; j < 4; ++j) {
                    const int r = r0 + j;
                    const int b = r >> 11, sy = r & 2047;
                    Vto[((size_t)(b * 16 + h) * 128 + c) * 2048 + sy] =
                        __float2bfloat16(acc[m][n][j]);
                }
            }
        }
    }
}

// ---------------- O-projection GEMM: fp32 out [4096][2048] (m97 structure) ----------------
__global__ __launch_bounds__(256, 2)
void gemm_o(const __hip_bfloat16* __restrict__ A,
            const __hip_bfloat16* __restrict__ Bt,
            float* __restrict__ Cout)
{
    const int K = 2048;
    __shared__ __hip_bfloat16 As[128 * 32];
    __shared__ __hip_bfloat16 Bs[128 * 32];
    const int tid = threadIdx.x;
    const int w = tid >> 6, l = tid & 63;
    const int m0 = blockIdx.x * 128, n0 = blockIdx.y * 128;
    const int wr = w >> 1, wc = w & 1;
    const int lr = l & 15, kh = l >> 4;

    f32x4 acc[4][4] = {};

    for (int kt = 0; kt < 64; ++kt) {
        const int kb = kt * 32;
#pragma unroll
        for (int i = 0; i < 2; ++i) {
            const int s = i * 256 + tid;
            const int r = s >> 2, ks = (s & 3) * 8;
            __builtin_amdgcn_global_load_lds(GLB_CAST(A + (size_t)(m0 + r) * K + kb + ks),
                                             LDS_CAST(As + (size_t)(i * 256 + w * 64) * 8),
                                             16, 0, 0);
            __builtin_amdgcn_global_load_lds(GLB_CAST(Bt + (size_t)(n0 + r) * K + kb + ks),
                                             LDS_CAST(Bs + (size_t)(i * 256 + w * 64) * 8),
                                             16, 0, 0);
        }
        __syncthreads();
        bf16x8 af[4], bfr[4];
#pragma unroll
        for (int m = 0; m < 4; ++m)
            af[m] = *(const bf16x8*)(As + (wr * 64 + m * 16 + lr) * 32 + kh * 8);
#pragma unroll
        for (int n = 0; n < 4; ++n)
            bfr[n] = *(const bf16x8*)(Bs + (wc * 64 + n * 16 + lr) * 32 + kh * 8);
#pragma unroll
        for (int m = 0; m < 4; ++m)
#pragma unroll
            for (int n = 0; n < 4; ++n)
                acc[m][n] = __builtin_amdgcn_mfma_f32_16x16x32_bf16(af[m], bfr[n], acc[m][n], 0, 0, 0);
        __syncthreads();
    }

#pragma unroll
    for (int m = 0; m < 4; ++m) {
        const int r0 = m0 + wr * 64 + m * 16 + kh * 4;
#pragma unroll
        for (int n = 0; n < 4; ++n) {
            const int c = n0 + wc * 64 + n * 16 + lr;
#pragma unroll
            for (int j = 0; j < 4; ++j)
                Cout[(size_t)(r0 + j) * 2048 + c] = acc[m][n][j];
        }
    }
}

// ---------------- causal flash attention: 4 waves x 32 q-rows, KVBLK=64 ----------------
// Block = 256 threads = 4 waves = 128 q-rows (group G); KV tile 64 double-buffered (64KB).
// Each wave owns 2 q-row groups: every K/V LDS fragment is read ONCE and feeds both
// groups' MFMAs. Same 40-piece decomposition: nt = 2G+2 tiles of 64; same OP/ML/merge.
__global__ __launch_bounds__(256, 2)
void flash_part(const __hip_bfloat16* __restrict__ Q,
                const __hip_bfloat16* __restrict__ K,
                const __hip_bfloat16* __restrict__ Vt,
                __hip_bfloat16* __restrict__ AO,
                __hip_bfloat16* __restrict__ OP,
                float* __restrict__ ML)
{
    const int bh = blockIdx.x;
    const int u  = blockIdx.y;
    const int tid = threadIdx.x, w = tid >> 6, l = tid & 63;
    const int lr = l & 15, hi = l >> 4;

    int G, part, P;
    if (u < 16)      { G = 12 + (u >> 2);            part = u & 3;   P = 4; }
    else if (u < 28) { int v = u - 16; G = 8 + v / 3; part = v % 3;  P = 3; }
    else if (u < 36) { int v = u - 28; G = 4 + (v >> 1); part = v & 1; P = 2; }
    else             { G = u - 36;                   part = 0;       P = 1; }
    const int nt = 2 * G + 2;                       // tiles of 64 kv
    const int t0 = (part * nt) / P, t1 = ((part + 1) * nt) / P;
    const bool split = (P > 1);
    const int qb = G * 128 + w * 32;                // wave owns 32 q-rows (2 groups of 16)
    const int q0 = qb + lr, q1 = qb + 16 + lr;

    const __hip_bfloat16* Qb = Q  + (size_t)bh * 2048 * 128;
    const __hip_bfloat16* Kb = K  + (size_t)bh * 2048 * 128;
    const __hip_bfloat16* Vb = Vt + (size_t)bh * 128 * 2048;

    __shared__ __align__(16) __hip_bfloat16 Ks[2][64 * 128];
    __shared__ __align__(16) __hip_bfloat16 Vs[2][128 * 64];

    // Q fragments for both groups: row qb+g*16+lr, k = kk*32 + hi*8
    bf16x8 qf[2][4];
#pragma unroll
    for (int g = 0; g < 2; ++g)
#pragma unroll
        for (int kk = 0; kk < 4; ++kk)
            qf[g][kk] = *(const bf16x8*)(Qb + (size_t)(qb + g * 16 + lr) * 128 + kk * 32 + hi * 8);

    // staging geometry: 1024 16B-slots per matrix per tile; 256 threads x 4 ops
    int rK[4], cK[4], rV[4], cV[4];
#pragma unroll
    for (int i = 0; i < 4; ++i) {
        const int slot = (i * 4 + w) * 64 + l;
        rK[i] = slot >> 4;                          // K row 0..63 (128 cols)
        cK[i] = ((slot & 15) ^ (rK[i] & 7)) * 8;
        rV[i] = slot >> 3;                          // V^T row (d) 0..127 (64 cols)
        cV[i] = ((slot & 7) ^ (rV[i] & 7)) * 8;
    }
    const int rsw7 = lr & 7;
    const int sA = lr + ((hi & 1) << 5);            // P-redistribution source lanes
    const int sB = sA + 16;
    const bool hsel = (hi >> 1) != 0;

#define STAGE(buf, t)                                                                        \
    {                                                                                        \
        const int kv0_ = (t) * 64;                                                           \
        _Pragma("unroll")                                                                    \
        for (int i = 0; i < 4; ++i) {                                                        \
            __builtin_amdgcn_global_load_lds(                                                \
                GLB_CAST(Kb + (size_t)(kv0_ + rK[i]) * 128 + cK[i]),                         \
                LDS_CAST(&Ks[buf][(i * 4 + w) * 512]), 16, 0, 0);                            \
            __builtin_amdgcn_global_load_lds(                                                \
                GLB_CAST(Vb + (size_t)rV[i] * 2048 + kv0_ + cV[i]),                          \
                LDS_CAST(&Vs[buf][(i * 4 + w) * 512]), 16, 0, 0);                            \
        }                                                                                    \
    }

    f32x4 o[2][8] = {};
    float mrow[2] = {-1e30f, -1e30f};
    float lrow[2] = {0.f, 0.f};

    int cur = 0;
    STAGE(0, t0);
    __syncthreads();

    for (int t = t0; t < t1; ++t) {
        if (t + 1 < t1) STAGE(cur ^ 1, t + 1);
        const __hip_bfloat16* Kc = &Ks[cur][0];
        const __hip_bfloat16* Vc = &Vs[cur][0];
        const int kv0 = t * 64;

        // S^T = K Q^T for both groups; each K fragment read once, used twice
        f32x4 sT[2][4] = {};
        __builtin_amdgcn_s_setprio(1);
#pragma unroll
        for (int f = 0; f < 4; ++f)
#pragma unroll
            for (int kk = 0; kk < 4; ++kk) {
                const bf16x8 kf = *(const bf16x8*)(Kc + (f * 16 + lr) * 128 +
                                                   ((kk * 4 + hi) ^ rsw7) * 8);
                sT[0][f] = __builtin_amdgcn_mfma_f32_16x16x32_bf16(kf, qf[0][kk], sT[0][f], 0, 0, 0);
                sT[1][f] = __builtin_amdgcn_mfma_f32_16x16x32_bf16(kf, qf[1][kk], sT[1][f], 0, 0, 0);
            }
        __builtin_amdgcn_s_setprio(0);

        // causal mask only on diagonal tiles (wave-uniform branch)
        if (kv0 + 63 > qb) {
#pragma unroll
            for (int g = 0; g < 2; ++g) {
                const int qown = g ? q1 : q0;
#pragma unroll
                for (int f = 0; f < 4; ++f)
#pragma unroll
                    for (int j = 0; j < 4; ++j) {
                        const int kv = kv0 + f * 16 + hi * 4 + j;
                        if (kv > qown) sT[g][f][j] = -1e30f;
                    }
            }
        }

        float pmax[2];
#pragma unroll
        for (int g = 0; g < 2; ++g) {
            float mx = sT[g][0][0];
#pragma unroll
            for (int f = 0; f < 4; ++f)
#pragma unroll
                for (int j = 0; j < 4; ++j) mx = fmaxf(mx, sT[g][f][j]);
            mx = fmaxf(mx, __shfl_xor(mx, 16));
            mx = fmaxf(mx, __shfl_xor(mx, 32));
            pmax[g] = mx;
        }

        // defer-max: rescale only when a running max grows by > 8*log2e
        if (!__all(pmax[0] <= mrow[0] + THR_LOG2 && pmax[1] <= mrow[1] + THR_LOG2)) {
#pragma unroll
            for (int g = 0; g < 2; ++g) {
                const float mnew = fmaxf(mrow[g], pmax[g]);
                const float alpha = exp2f(mrow[g] - mnew);
                mrow[g] = mnew;
                lrow[g] *= alpha;
                float aj[4];
#pragma unroll
                for (int j = 0; j < 4; ++j)
                    aj[j] = __shfl(alpha, (l & 48) | (hi * 4 + j), 64);
#pragma unroll
                for (int dn = 0; dn < 8; ++dn)
#pragma unroll
                    for (int j = 0; j < 4; ++j) o[g][dn][j] *= aj[j];
            }
        }

        // P = exp2(S - m), row sums; pack + redistribute to PV A-fragments
        union { unsigned u[4]; bf16x8 v; } pa[2][2];
#pragma unroll
        for (int g = 0; g < 2; ++g) {
            float rs = 0.f;
#pragma unroll
            for (int f = 0; f < 4; ++f)
#pragma unroll
                for (int j = 0; j < 4; ++j) {
                    const float pv = exp2f(sT[g][f][j] - mrow[g]);
                    sT[g][f][j] = pv;
                    rs += pv;
                }
            rs += __shfl_xor(rs, 16);
            rs += __shfl_xor(rs, 32);
            lrow[g] += rs;

            unsigned wds[8];
#pragma unroll
            for (int f = 0; f < 4; ++f)
#pragma unroll
                for (int hh = 0; hh < 2; ++hh)
                    wds[f * 2 + hh] = (unsigned)bf16_bits(sT[g][f][hh * 2]) |
                                      ((unsigned)bf16_bits(sT[g][f][hh * 2 + 1]) << 16);
            unsigned av[8], bv[8];
#pragma unroll
            for (int i = 0; i < 8; ++i) {
                av[i] = __shfl((int)wds[i], sA, 64);
                bv[i] = __shfl((int)wds[i], sB, 64);
            }
            pa[g][0].u[0] = hsel ? av[2] : av[0];
            pa[g][0].u[1] = hsel ? av[3] : av[1];
            pa[g][0].u[2] = hsel ? bv[2] : bv[0];
            pa[g][0].u[3] = hsel ? bv[3] : bv[1];
            pa[g][1].u[0] = hsel ? av[6] : av[4];
            pa[g][1].u[1] = hsel ? av[7] : av[5];
            pa[g][1].u[2] = hsel ? bv[6] : bv[4];
            pa[g][1].u[3] = hsel ? bv[7] : bv[5];
        }

        // PV: each V fragment read once, used by both groups (4 MFMAs per 2 reads)
        __builtin_amdgcn_s_setprio(1);
#pragma unroll
        for (int dn = 0; dn < 8; ++dn) {
            const int vrow = (dn * 16 + lr) * 64;
            const bf16x8 vf0 = *(const bf16x8*)(Vc + vrow + ((0 + hi) ^ rsw7) * 8);
            const bf16x8 vf1 = *(const bf16x8*)(Vc + vrow + ((4 + hi) ^ rsw7) * 8);
            o[0][dn] = __builtin_amdgcn_mfma_f32_16x16x32_bf16(pa[0][0].v, vf0, o[0][dn], 0, 0, 0);
            o[1][dn] = __builtin_amdgcn_mfma_f32_16x16x32_bf16(pa[1][0].v, vf0, o[1][dn], 0, 0, 0);
            o[0][dn] = __builtin_amdgcn_mfma_f32_16x16x32_bf16(pa[0][1].v, vf1, o[0][dn], 0, 0, 0);
            o[1][dn] = __builtin_amdgcn_mfma_f32_16x16x32_bf16(pa[1][1].v, vf1, o[1][dn], 0, 0, 0);
        }
        __builtin_amdgcn_s_setprio(0);

        __syncthreads();
        cur ^= 1;
    }
#undef STAGE

    if (!split) {
#pragma unroll
        for (int g = 0; g < 2; ++g) {
            float linv[4];
#pragma unroll
            for (int j = 0; j < 4; ++j)
                linv[j] = 1.0f / __shfl(lrow[g], (l & 48) | (hi * 4 + j), 64);
#pragma unroll
            for (int j = 0; j < 4; ++j) {
                const int q = qb + g * 16 + hi * 4 + j;
                const size_t rb = ((size_t)(bh >> 4) * 2048 + q) * 2048 + (size_t)(bh & 15) * 128;
#pragma unroll
                for (int dn = 0; dn < 8; ++dn)
                    AO[rb + dn * 16 + lr] = __float2bfloat16(o[g][dn][j] * linv[j]);
            }
        }
    } else {
        const int base = (G < 8) ? (G - 4) * 2 : ((G < 12) ? 8 + (G - 8) * 3
                                                           : 20 + (G - 12) * 4);
        const int pidx = bh * 36 + base + part;
#pragma unroll
        for (int g = 0; g < 2; ++g) {
#pragma unroll
            for (int j = 0; j < 4; ++j) {
                const int row = w * 32 + g * 16 + hi * 4 + j;   // 0..127 within group
#pragma unroll
                for (int dn = 0; dn < 8; ++dn)
                    OP[((size_t)pidx * 128 + row) * 128 + dn * 16 + lr] =
                        __float2bfloat16(o[g][dn][j]);
            }
            if (l < 16) {
                const int row = w * 32 + g * 16 + l;
                ML[((size_t)pidx * 128 + row) * 2]     = mrow[g];   // log2-domain m
                ML[((size_t)pidx * 128 + row) * 2 + 1] = lrow[g];
            }
        }
    }
}

// ---------------- merge P in {2,3,4} partials per split group (G=4..15) ----------------
__global__ void flash_merge(const __hip_bfloat16* __restrict__ OP,
                            const float* __restrict__ ML,
                            __hip_bfloat16* __restrict__ AO)
{
    const int gi = blockIdx.x % 12, bh = blockIdx.x / 12;
    const int G = 4 + gi;
    const int P = (G < 8) ? 2 : ((G < 12) ? 3 : 4);
    const int base = (G < 8) ? (G - 4) * 2 : ((G < 12) ? 8 + (G - 8) * 3
                                                       : 20 + (G - 12) * 4);
    const int pidx0 = bh * 36 + base;
    const int t = threadIdx.x, r = t >> 1, c0 = (t & 1) * 64;

    float m[4], lv[4];
    float M = -1e30f;
#pragma unroll
    for (int p = 0; p < 4; ++p) if (p < P) {
        m[p]  = ML[((size_t)(pidx0 + p) * 128 + r) * 2];
        lv[p] = ML[((size_t)(pidx0 + p) * 128 + r) * 2 + 1];
        M = fmaxf(M, m[p]);
    }
    float wgt[4];
    float den = 0.f;
#pragma unroll
    for (int p = 0; p < 4; ++p) if (p < P) {
        wgt[p] = exp2f(m[p] - M);   // log2-domain merge
        den += lv[p] * wgt[p];
    }
    const float inv = 1.0f / den;

    const int q = G * 128 + r;
    __hip_bfloat16* out = AO + ((size_t)(bh >> 4) * 2048 + q) * 2048 + (size_t)(bh & 15) * 128 + c0;

#pragma unroll
    for (int ch = 0; ch < 8; ++ch) {
        float acc[8] = {0.f, 0.f, 0.f, 0.f, 0.f, 0.f, 0.f, 0.f};
#pragma unroll
        for (int p = 0; p < 4; ++p) if (p < P) {
            const bf16x8 v = *(const bf16x8*)(OP + ((size_t)(pidx0 + p) * 128 + r) * 128 + c0 + ch * 8);
#pragma unroll
            for (int i = 0; i < 8; ++i) {
                __hip_bfloat16 hv;
                *(short*)&hv = v[i];
                acc[i] += __bfloat162float(hv) * wgt[p];
            }
        }
        union { unsigned short us[8]; bf16x8 v; } rr;
#pragma unroll
        for (int i = 0; i < 8; ++i) rr.us[i] = bf16_bits(acc[i] * inv);
        *(bf16x8*)(out + ch * 8) = rr.v;
    }
}

extern "C" void kernel_launch(void* const* d_in, const int* in_sizes, int n_in,
                              void* d_out, int out_size, void* d_ws, size_t ws_size,
                              hipStream_t stream) {
    (void)in_sizes; (void)n_in; (void)out_size; (void)ws_size;
    const float* x  = (const float*)d_in[0];
    const float* Wq = (const float*)d_in[1];
    const float* Wk = (const float*)d_in[2];
    const float* Wv = (const float*)d_in[3];
    const float* Wo = (const float*)d_in[4];

    char* p = (char*)d_ws;
    auto carve = [&](size_t bytes) -> char* {
        char* r = p;
        p += (bytes + 255) & ~(size_t)255;
        return r;
    };
    __hip_bfloat16* xb  = (__hip_bfloat16*)carve(4096ull * 2048 * 2);  // reused as AO
    __hip_bfloat16* Wqb = (__hip_bfloat16*)carve(2048ull * 2048 * 2);
    __hip_bfloat16* Wkb = (__hip_bfloat16*)carve(2048ull * 2048 * 2);
    __hip_bfloat16* Wvb = (__hip_bfloat16*)carve(2048ull * 2048 * 2);
    __hip_bfloat16* Wob = (__hip_bfloat16*)carve(2048ull * 2048 * 2);
    __hip_bfloat16* Qb  = (__hip_bfloat16*)carve(32ull * 2048 * 128 * 2);
    __hip_bfloat16* Kb  = (__hip_bfloat16*)carve(32ull * 2048 * 128 * 2);
    __hip_bfloat16* Vtb = (__hip_bfloat16*)carve(32ull * 128 * 2048 * 2);
    __hip_bfloat16* OPb = (__hip_bfloat16*)carve(32ull * 36 * 128 * 128 * 2);  // partial O
    float*          MLb = (float*)carve(32ull * 36 * 128 * 2 * 4);             // partial m,l

    cvt_all<<<12288, 256, 0, stream>>>(x, Wq, Wk, Wv, Wo, xb, Wqb, Wkb, Wvb, Wob);

    gemm_qkv<<<dim3(32, 48), 256, 0, stream>>>(xb, Wqb, Wkb, Wvb, Qb, Kb, Vtb);

    flash_part<<<dim3(32, 40), 256, 0, stream>>>(Qb, Kb, Vtb, xb /* AO */, OPb, MLb);
    flash_merge<<<384, 256, 0, stream>>>(OPb, MLb, xb /* AO */);

    gemm_o<<<dim3(32, 16), 256, 0, stream>>>(xb, Wob, (float*)d_out);
}